// Round 8
// baseline (141.542 us; speedup 1.0000x reference)
//
#include <hip/hip_runtime.h>
#include <math.h>

#define BATCH 2048

typedef __attribute__((ext_vector_type(4))) int i32x4;
typedef __attribute__((ext_vector_type(16))) int i32x16;

__device__ __forceinline__ int sdot4(int a, int b, int c) {
    return __builtin_amdgcn_sdot4(a, b, c, false);
}

__device__ __forceinline__ float fsign(float v) {
    return v > 0.f ? 1.f : (v < 0.f ? -1.f : 0.f);
}

// One fused prep kernel: wf1 binarize | w2 pack | wf2 binarize | k1 const table
__global__ void prep_all(const float* __restrict__ w1, const float* __restrict__ b1,
                         const float* __restrict__ g1, const float* __restrict__ be1,
                         const float* __restrict__ m1, const float* __restrict__ v1,
                         const float* __restrict__ w2, const float* __restrict__ wf1,
                         const float* __restrict__ wf2,
                         signed char* __restrict__ w2p, signed char* __restrict__ wf1s,
                         signed char* __restrict__ wf2p, float* __restrict__ k1c) {
    int i = blockIdx.x * 256 + threadIdx.x;
    if (i < 2359296) {  // wf1 sign (natural [1024][2304] layout)
        float v = wf1[i];
        wf1s[i] = v > 0.f ? 1 : (v < 0.f ? -1 : 0);
        return;
    }
    i -= 2359296;
    if (i < 51200) {    // w2 [64][32][5][5] -> w2p [64][25][32]
        int ic = i % 32, tap = (i / 32) % 25, oc = i / 800;
        float v = w2[(oc * 32 + ic) * 25 + tap];
        w2p[i] = v > 0.f ? 1 : (v < 0.f ? -1 : 0);
        return;
    }
    i -= 51200;
    if (i < 10240) {    // wf2 sign
        float v = wf2[i];
        wf2p[i] = v > 0.f ? 1 : (v < 0.f ? -1 : 0);
        return;
    }
    i -= 10240;
    if (i < 416) {      // k1c [32][16] = {sw0..8, bias, m, sc, bb}
        int oc = i / 13, s = i - oc * 13;
        float r;
        if (s < 9) r = fsign(w1[oc * 9 + s]);
        else if (s == 9) r = b1[oc];
        else if (s == 10) r = m1[oc];
        else if (s == 11) r = g1[oc] / sqrtf(v1[oc] + 1e-5f);
        else r = be1[oc];
        k1c[oc * 16 + s] = r;
    }
}

// K1: conv1 + bias + BN + sign + pool2 -> act1 channel-last [B][13][13][32] int8
// One LANE per (pool cell, oc): oc = lane&31 -> per-lane consts in VGPRs.
__global__ __launch_bounds__(256) void k1_conv1(
        const float* __restrict__ x, const float* __restrict__ k1c,
        signed char* __restrict__ act1) {
    int t = blockIdx.x * 256 + threadIdx.x;  // 43264*256 = 2048*169*32 exact
    int oc = t & 31;
    int cell = t >> 5;                       // b*169 + pix
    int pix = cell % 169, b = cell / 169;
    int py = pix / 13, px = pix % 13;

    const float* c = k1c + oc * 16;
    float sw[9];
#pragma unroll
    for (int i = 0; i < 9; i++) sw[i] = c[i];
    float bias = c[9], m = c[10], sc = c[11], bb = c[12];

    const float* xb = x + b * 784 + (2 * py) * 28 + 2 * px;
    float xr[4][4];
#pragma unroll
    for (int dy = 0; dy < 4; dy++)
#pragma unroll
        for (int dx = 0; dx < 4; dx++) xr[dy][dx] = xb[dy * 28 + dx];

    float best = -1e30f;
#pragma unroll
    for (int q = 0; q < 4; q++) {
        int dyp = q >> 1, dxp = q & 1;
        float acc = 0.f;
#pragma unroll
        for (int ky = 0; ky < 3; ky++)
#pragma unroll
            for (int kx = 0; kx < 3; kx++)
                acc += xr[dyp + ky][dxp + kx] * sw[ky * 3 + kx];
        float bn = (acc + bias - m) * sc + bb;  // same assoc as prior rounds
        best = fmaxf(best, bn);                 // sign(max) == max(sign)
    }
    act1[(size_t)cell * 32 + oc] = (signed char)fsign(best);
}

// K2: conv2 as implicit-GEMM MFMA i8. Block = 2 images, 9 waves.
#define K2_IMG_STRIDE 9248          // 17*17*32
#define K2_WOFF 18496               // 2*9248
__device__ __forceinline__ void k2_epilogue(i32x16 A, int oc, int wave, int kh, int b0,
                                            const float* __restrict__ b2,
                                            const float* __restrict__ g2,
                                            const float* __restrict__ be2,
                                            const float* __restrict__ m2,
                                            const float* __restrict__ v2,
                                            signed char* __restrict__ act2) {
    float bias = b2[oc], mm = m2[oc];
    float sc = g2[oc] / sqrtf(v2[oc] + 1e-5f), bb = be2[oc];
#pragma unroll
    for (int g = 0; g < 4; g++) {
        int qo = wave * 8 + kh + 2 * g;      // 0..71 pool cell (2 images)
        int imo = qo / 36, qqo = qo - imo * 36;
        float best = -2.f;
#pragma unroll
        for (int jj = 0; jj < 4; jj++) {     // 4 pool partners live in reg quad
            float z = (float)A[g * 4 + jj] + bias;
            float bn = (z - mm) * sc + bb;
            best = fmaxf(best, fsign(bn));
        }
        act2[((size_t)(b0 + imo) * 64 + oc) * 36 + qqo] = (signed char)best;
    }
}

__global__ __launch_bounds__(576) void k2_mfma(
        const signed char* __restrict__ act1, const signed char* __restrict__ w2p,
        const float* __restrict__ b2, const float* __restrict__ g2,
        const float* __restrict__ be2, const float* __restrict__ m2,
        const float* __restrict__ v2, signed char* __restrict__ act2) {
    __shared__ __align__(16) signed char smem[69696];  // 18496 + 51200
    int tid = threadIdx.x;
    int b0 = blockIdx.x * 2;
    i32x4* s4 = (i32x4*)smem;
    i32x4 z4 = {0, 0, 0, 0};
    for (int i = tid; i < 1156; i += 576) s4[i] = z4;
    __syncthreads();
    {
        const i32x4* src = (const i32x4*)(act1 + (size_t)b0 * 5408);
        for (int i = tid; i < 676; i += 576) {
            int im = i / 338, r = i - im * 338;
            int pix = r >> 1, half = r & 1;
            int yy = pix / 13 + 2, xx = pix % 13 + 2;
            *(i32x4*)(smem + im * K2_IMG_STRIDE + (yy * 17 + xx) * 32 + half * 16) = src[i];
        }
        const i32x4* wsrc = (const i32x4*)w2p;
        for (int i = tid; i < 3200; i += 576) {
            int oc = i / 50, r = i - oc * 50;
            int tap = r >> 1, half = r & 1;
            *(i32x4*)(smem + K2_WOFF + tap * 2048 + oc * 32 + half * 16) = wsrc[i];
        }
    }
    __syncthreads();

    int wave = tid >> 6, lane = tid & 63;
    int lrow = lane & 31, kh = lane >> 5;
    int m = wave * 32 + lrow;
    int q = m >> 2, j = m & 3;
    int img = q / 36, qq = q - img * 36;
    int oy = 2 * (qq / 6) + (j >> 1);
    int ox = 2 * (qq - (qq / 6) * 6) + (j & 1);
    const signed char* abase = smem + img * K2_IMG_STRIDE + (oy * 17 + ox) * 32 + kh * 16;
    const signed char* bbase = smem + K2_WOFF + lrow * 32 + kh * 16;

    i32x16 acc0 = {0};
    i32x16 acc1 = {0};
#pragma unroll 5
    for (int tap = 0; tap < 25; ++tap) {
        int ky = tap / 5, kx = tap - (tap / 5) * 5;
        i32x4 a = *(const i32x4*)(abase + (ky * 17 + kx) * 32);
        i32x4 w0 = *(const i32x4*)(bbase + tap * 2048);
        i32x4 w1 = *(const i32x4*)(bbase + tap * 2048 + 1024);
        acc0 = __builtin_amdgcn_mfma_i32_32x32x32_i8(a, w0, acc0, 0, 0, 0);
        acc1 = __builtin_amdgcn_mfma_i32_32x32x32_i8(a, w1, acc1, 0, 0, 0);
    }
    k2_epilogue(acc0, lrow,      wave, kh, b0, b2, g2, be2, m2, v2, act2);
    k2_epilogue(acc1, 32 + lrow, wave, kh, b0, b2, g2, be2, m2, v2, act2);
}

// K3: fc1 as MFMA i8 GEMM 2048x1024x2304. Wave tile 32x64, K-split x2, 4 waves/block.
__global__ __launch_bounds__(256) void k3_mfma(
        const signed char* __restrict__ act2, const signed char* __restrict__ wf1s,
        const float* __restrict__ bf1, const float* __restrict__ gf1,
        const float* __restrict__ bef1, const float* __restrict__ mf1,
        const float* __restrict__ vf1, signed char* __restrict__ act3) {
    __shared__ int red[2][2048];
    int tid = threadIdx.x;
    int l = tid & 63, w = tid >> 6;
    int tile_local = w >> 1, khalf = w & 1;
    int tile = blockIdx.x * 2 + tile_local;       // 0..1023
    int tn = tile & 15, tm = tile >> 4;           // tn: N/64, tm: M/32
    int lrow = l & 31, kh = l >> 5;

    const signed char* aptr = act2 + (size_t)(tm * 32 + lrow) * 2304 + khalf * 1152 + kh * 16;
    const signed char* bptr = wf1s + (size_t)(tn * 64 + lrow) * 2304 + khalf * 1152 + kh * 16;

    i32x16 acc0 = {0};
    i32x16 acc1 = {0};
#pragma unroll 6
    for (int ks = 0; ks < 36; ++ks) {
        i32x4 a  = *(const i32x4*)(aptr + ks * 32);
        i32x4 b0 = *(const i32x4*)(bptr + ks * 32);
        i32x4 b1 = *(const i32x4*)(bptr + 32 * 2304 + ks * 32);
        acc0 = __builtin_amdgcn_mfma_i32_32x32x32_i8(a, b0, acc0, 0, 0, 0);
        acc1 = __builtin_amdgcn_mfma_i32_32x32x32_i8(a, b1, acc1, 0, 0, 0);
    }
    if (khalf) {
        int* rp = &red[tile_local][0];
#pragma unroll
        for (int r = 0; r < 16; r++) rp[r * 64 + l] = acc0[r];
#pragma unroll
        for (int r = 0; r < 16; r++) rp[(r + 16) * 64 + l] = acc1[r];
    }
    __syncthreads();
    if (!khalf) {
        const int* rp = &red[tile_local][0];
#pragma unroll
        for (int r = 0; r < 16; r++) acc0[r] += rp[r * 64 + l];
#pragma unroll
        for (int r = 0; r < 16; r++) acc1[r] += rp[(r + 16) * 64 + l];

        int col0 = tn * 64 + lrow;
        int col1 = col0 + 32;
        float bi0 = bf1[col0], m0 = mf1[col0];
        float sc0 = gf1[col0] / sqrtf(vf1[col0] + 1e-5f), bb0 = bef1[col0];
        float bi1 = bf1[col1], m1 = mf1[col1];
        float sc1 = gf1[col1] / sqrtf(vf1[col1] + 1e-5f), bb1 = bef1[col1];
#pragma unroll
        for (int r = 0; r < 16; r++) {
            int row = tm * 32 + (r & 3) + 8 * (r >> 2) + 4 * kh;
            float bn0 = ((float)acc0[r] + bi0 - m0) * sc0 + bb0;
            float bn1 = ((float)acc1[r] + bi1 - m1) * sc1 + bb1;
            act3[(size_t)row * 1024 + col0] = (signed char)fsign(bn0);
            act3[(size_t)row * 1024 + col1] = (signed char)fsign(bn1);
        }
    }
}

// K4: fc2 (1024->10) + bias + BN + log_softmax. One wave per image.
__global__ void k4_fc2(const signed char* __restrict__ act3, const signed char* __restrict__ swf2,
                       const float* __restrict__ bf2, const float* __restrict__ gf2,
                       const float* __restrict__ bef2, const float* __restrict__ mf2,
                       const float* __restrict__ vf2, float* __restrict__ out) {
    int wid = (blockIdx.x * 256 + threadIdx.x) >> 6;
    int lane = threadIdx.x & 63;
    if (wid >= BATCH) return;
    const int* hd = (const int*)act3 + (size_t)wid * 256;
    const int* wd = (const int*)swf2;
    int acc[10];
#pragma unroll
    for (int o = 0; o < 10; o++) acc[o] = 0;
#pragma unroll
    for (int i = 0; i < 4; i++) {
        int k4 = i * 64 + lane;
        int hv = hd[k4];
#pragma unroll
        for (int o = 0; o < 10; o++)
            acc[o] = sdot4(hv, wd[o * 256 + k4], acc[o]);
    }
#pragma unroll
    for (int o = 0; o < 10; o++)
#pragma unroll
        for (int s = 32; s > 0; s >>= 1) acc[o] += __shfl_xor(acc[o], s);
    if (lane == 0) {
        float logit[10];
        float mx = -1e30f;
#pragma unroll
        for (int o = 0; o < 10; o++) {
            float z = (float)acc[o] + bf2[o];
            float bn = (z - mf2[o]) * (gf2[o] / sqrtf(vf2[o] + 1e-5f)) + bef2[o];
            logit[o] = bn;
            mx = fmaxf(mx, bn);
        }
        float s = 0.f;
#pragma unroll
        for (int o = 0; o < 10; o++) s += expf(logit[o] - mx);
        float lse = mx + logf(s);
#pragma unroll
        for (int o = 0; o < 10; o++) out[(size_t)wid * 10 + o] = logit[o] - lse;
    }
}

extern "C" void kernel_launch(void* const* d_in, const int* in_sizes, int n_in,
                              void* d_out, int out_size, void* d_ws, size_t ws_size,
                              hipStream_t stream) {
    const float* x   = (const float*)d_in[0];
    const float* w1  = (const float*)d_in[1];
    const float* b1  = (const float*)d_in[2];
    const float* g1  = (const float*)d_in[3];
    const float* be1 = (const float*)d_in[4];
    const float* m1  = (const float*)d_in[5];
    const float* v1  = (const float*)d_in[6];
    const float* w2  = (const float*)d_in[7];
    const float* b2  = (const float*)d_in[8];
    const float* g2  = (const float*)d_in[9];
    const float* be2 = (const float*)d_in[10];
    const float* m2  = (const float*)d_in[11];
    const float* v2  = (const float*)d_in[12];
    const float* wf1 = (const float*)d_in[13];
    const float* bf1 = (const float*)d_in[14];
    const float* gf1 = (const float*)d_in[15];
    const float* bef1= (const float*)d_in[16];
    const float* mf1 = (const float*)d_in[17];
    const float* vf1 = (const float*)d_in[18];
    const float* wf2 = (const float*)d_in[19];
    const float* bf2 = (const float*)d_in[20];
    const float* gf2 = (const float*)d_in[21];
    const float* bef2= (const float*)d_in[22];
    const float* mf2 = (const float*)d_in[23];
    const float* vf2 = (const float*)d_in[24];
    float* out = (float*)d_out;

    // ws layout (all int8 unless noted)
    char* ws = (char*)d_ws;
    signed char* act1 = (signed char*)ws;                  // 2048*169*32   = 11,075,584
    signed char* act2 = act1 + 11075584;                   // 2048*2304     =  4,718,592
    signed char* act3 = act2 + 4718592;                    // 2048*1024     =  2,097,152
    signed char* w2p  = act3 + 2097152;                    // 64*25*32      =     51,200
    signed char* wf1s = w2p + 51200;                       // 1024*2304     =  2,359,296
    signed char* wf2p = wf1s + 2359296;                    // 10*1024       =     10,240
    float* k1c = (float*)(wf2p + 10240);                   // 32*16 floats  =      2,048 B

    // fused prep: 2,359,296 + 51,200 + 10,240 + 416 = 2,421,152 elems
    prep_all<<<9458, 256, 0, stream>>>(w1, b1, g1, be1, m1, v1, w2, wf1, wf2,
                                       w2p, wf1s, wf2p, k1c);

    k1_conv1<<<43264, 256, 0, stream>>>(x, k1c, act1);

    k2_mfma<<<1024, 576, 0, stream>>>(act1, w2p, b2, g2, be2, m2, v2, act2);

    k3_mfma<<<512, 256, 0, stream>>>(act2, wf1s, bf1, gf1, bef1, mf1, vf1, act3);

    k4_fc2<<<512, 256, 0, stream>>>(act3, wf2p, bf2, gf2, bef2, mf2, vf2, out);
}

// Round 9
// 100.930 us; speedup vs baseline: 1.4024x; 1.4024x over previous
//
#include <hip/hip_runtime.h>
#include <math.h>

#define BATCH 2048

typedef __attribute__((ext_vector_type(4))) int i32x4;
typedef __attribute__((ext_vector_type(16))) int i32x16;

__device__ __forceinline__ int sdot4(int a, int b, int c) {
    return __builtin_amdgcn_sdot4(a, b, c, false);
}

__device__ __forceinline__ float fsign(float v) {
    return v > 0.f ? 1.f : (v < 0.f ? -1.f : 0.f);
}

// One fused prep kernel: wf1 binarize | w2 pack | wf2 binarize | k1 const table
__global__ void prep_all(const float* __restrict__ w1, const float* __restrict__ b1,
                         const float* __restrict__ g1, const float* __restrict__ be1,
                         const float* __restrict__ m1, const float* __restrict__ v1,
                         const float* __restrict__ w2, const float* __restrict__ wf1,
                         const float* __restrict__ wf2,
                         signed char* __restrict__ w2p, signed char* __restrict__ wf1s,
                         signed char* __restrict__ wf2p, float* __restrict__ k1c) {
    int i = blockIdx.x * 256 + threadIdx.x;
    if (i < 2359296) {  // wf1 sign (natural [1024][2304] layout)
        float v = wf1[i];
        wf1s[i] = v > 0.f ? 1 : (v < 0.f ? -1 : 0);
        return;
    }
    i -= 2359296;
    if (i < 51200) {    // w2 [64][32][5][5] -> w2p [64][25][32]
        int ic = i % 32, tap = (i / 32) % 25, oc = i / 800;
        float v = w2[(oc * 32 + ic) * 25 + tap];
        w2p[i] = v > 0.f ? 1 : (v < 0.f ? -1 : 0);
        return;
    }
    i -= 51200;
    if (i < 10240) {    // wf2 sign
        float v = wf2[i];
        wf2p[i] = v > 0.f ? 1 : (v < 0.f ? -1 : 0);
        return;
    }
    i -= 10240;
    if (i < 416) {      // k1c [32][16] = {sw0..8, bias, m, sc, bb}
        int oc = i / 13, s = i - oc * 13;
        float r;
        if (s < 9) r = fsign(w1[oc * 9 + s]);
        else if (s == 9) r = b1[oc];
        else if (s == 10) r = m1[oc];
        else if (s == 11) r = g1[oc] / sqrtf(v1[oc] + 1e-5f);
        else r = be1[oc];
        k1c[oc * 16 + s] = r;
    }
}

// K1: conv1 + bias + BN + sign + pool2 -> act1 channel-last [B][13][13][32] int8
// Block = one image (x staged in LDS). lane oc = tid&31 (consts in VGPRs),
// cell-group g = tid>>5 walks cells g, g+8, g+16, ...
__global__ __launch_bounds__(256) void k1_conv1(
        const float* __restrict__ x, const float* __restrict__ k1c,
        signed char* __restrict__ act1) {
    __shared__ __align__(16) float xs[784];
    int b = blockIdx.x, tid = threadIdx.x;
    if (tid < 196) ((float4*)xs)[tid] = ((const float4*)(x + (size_t)b * 784))[tid];
    __syncthreads();

    int oc = tid & 31, g = tid >> 5;
    const float* c = k1c + oc * 16;
    float sw[9];
#pragma unroll
    for (int i = 0; i < 9; i++) sw[i] = c[i];
    float bias = c[9], m = c[10], sc = c[11], bb = c[12];
    signed char* dst = act1 + (size_t)b * 5408 + oc;

    for (int i = 0; i < 22; i++) {
        int cell = i * 8 + g;
        if (cell < 169) {
            int py = cell / 13, px = cell - py * 13;
            const float* wnd = xs + py * 56 + px * 2;  // (2py)*28 + 2px, even idx
            float xr[4][4];
#pragma unroll
            for (int dy = 0; dy < 4; dy++) {
                float2 lo = *(const float2*)(wnd + dy * 28);
                float2 hi = *(const float2*)(wnd + dy * 28 + 2);
                xr[dy][0] = lo.x; xr[dy][1] = lo.y;
                xr[dy][2] = hi.x; xr[dy][3] = hi.y;
            }
            float maxacc = -1e30f;
#pragma unroll
            for (int q = 0; q < 4; q++) {
                int dyp = q >> 1, dxp = q & 1;
                float acc = 0.f;
#pragma unroll
                for (int ky = 0; ky < 3; ky++)
#pragma unroll
                    for (int kx = 0; kx < 3; kx++)
                        acc += xr[dyp + ky][dxp + kx] * sw[ky * 3 + kx];
                maxacc = fmaxf(maxacc, acc);   // BN monotone (sc>0): max commutes
            }
            float bn = (maxacc + bias - m) * sc + bb;  // same assoc as before
            dst[(size_t)cell * 32] = (signed char)fsign(bn);
        }
    }
}

// K2: conv2 as implicit-GEMM MFMA i8. Block = 2 images, 9 waves.
#define K2_IMG_STRIDE 9248          // 17*17*32
#define K2_WOFF 18496               // 2*9248
__device__ __forceinline__ void k2_epilogue(i32x16 A, int oc, int wave, int kh, int b0,
                                            const float* __restrict__ b2,
                                            const float* __restrict__ g2,
                                            const float* __restrict__ be2,
                                            const float* __restrict__ m2,
                                            const float* __restrict__ v2,
                                            signed char* __restrict__ act2) {
    float bias = b2[oc], mm = m2[oc];
    float sc = g2[oc] / sqrtf(v2[oc] + 1e-5f), bb = be2[oc];
#pragma unroll
    for (int g = 0; g < 4; g++) {
        int qo = wave * 8 + kh + 2 * g;      // 0..71 pool cell (2 images)
        int imo = qo / 36, qqo = qo - imo * 36;
        float best = -2.f;
#pragma unroll
        for (int jj = 0; jj < 4; jj++) {     // 4 pool partners live in reg quad
            float z = (float)A[g * 4 + jj] + bias;
            float bn = (z - mm) * sc + bb;
            best = fmaxf(best, fsign(bn));
        }
        act2[((size_t)(b0 + imo) * 64 + oc) * 36 + qqo] = (signed char)best;
    }
}

__global__ __launch_bounds__(576) void k2_mfma(
        const signed char* __restrict__ act1, const signed char* __restrict__ w2p,
        const float* __restrict__ b2, const float* __restrict__ g2,
        const float* __restrict__ be2, const float* __restrict__ m2,
        const float* __restrict__ v2, signed char* __restrict__ act2) {
    __shared__ __align__(16) signed char smem[69696];  // 18496 + 51200
    int tid = threadIdx.x;
    int b0 = blockIdx.x * 2;
    i32x4* s4 = (i32x4*)smem;
    i32x4 z4 = {0, 0, 0, 0};
    for (int i = tid; i < 1156; i += 576) s4[i] = z4;
    __syncthreads();
    {
        const i32x4* src = (const i32x4*)(act1 + (size_t)b0 * 5408);
        for (int i = tid; i < 676; i += 576) {
            int im = i / 338, r = i - im * 338;
            int pix = r >> 1, half = r & 1;
            int yy = pix / 13 + 2, xx = pix % 13 + 2;
            *(i32x4*)(smem + im * K2_IMG_STRIDE + (yy * 17 + xx) * 32 + half * 16) = src[i];
        }
        const i32x4* wsrc = (const i32x4*)w2p;
        for (int i = tid; i < 3200; i += 576) {
            int oc = i / 50, r = i - oc * 50;
            int tap = r >> 1, half = r & 1;
            *(i32x4*)(smem + K2_WOFF + tap * 2048 + oc * 32 + half * 16) = wsrc[i];
        }
    }
    __syncthreads();

    int wave = tid >> 6, lane = tid & 63;
    int lrow = lane & 31, kh = lane >> 5;
    int m = wave * 32 + lrow;
    int q = m >> 2, j = m & 3;
    int img = q / 36, qq = q - img * 36;
    int oy = 2 * (qq / 6) + (j >> 1);
    int ox = 2 * (qq - (qq / 6) * 6) + (j & 1);
    const signed char* abase = smem + img * K2_IMG_STRIDE + (oy * 17 + ox) * 32 + kh * 16;
    const signed char* bbase = smem + K2_WOFF + lrow * 32 + kh * 16;

    i32x16 acc0 = {0};
    i32x16 acc1 = {0};
#pragma unroll 5
    for (int tap = 0; tap < 25; ++tap) {
        int ky = tap / 5, kx = tap - (tap / 5) * 5;
        i32x4 a = *(const i32x4*)(abase + (ky * 17 + kx) * 32);
        i32x4 w0 = *(const i32x4*)(bbase + tap * 2048);
        i32x4 w1 = *(const i32x4*)(bbase + tap * 2048 + 1024);
        acc0 = __builtin_amdgcn_mfma_i32_32x32x32_i8(a, w0, acc0, 0, 0, 0);
        acc1 = __builtin_amdgcn_mfma_i32_32x32x32_i8(a, w1, acc1, 0, 0, 0);
    }
    k2_epilogue(acc0, lrow,      wave, kh, b0, b2, g2, be2, m2, v2, act2);
    k2_epilogue(acc1, 32 + lrow, wave, kh, b0, b2, g2, be2, m2, v2, act2);
}

// K3: fc1 as MFMA i8 GEMM 2048x1024x2304. Wave tile 32x64, K-split x2, 4 waves/block.
__global__ __launch_bounds__(256) void k3_mfma(
        const signed char* __restrict__ act2, const signed char* __restrict__ wf1s,
        const float* __restrict__ bf1, const float* __restrict__ gf1,
        const float* __restrict__ bef1, const float* __restrict__ mf1,
        const float* __restrict__ vf1, signed char* __restrict__ act3) {
    __shared__ int red[2][2048];
    int tid = threadIdx.x;
    int l = tid & 63, w = tid >> 6;
    int tile_local = w >> 1, khalf = w & 1;
    int tile = blockIdx.x * 2 + tile_local;       // 0..1023
    int tn = tile & 15, tm = tile >> 4;           // tn: N/64, tm: M/32
    int lrow = l & 31, kh = l >> 5;

    const signed char* aptr = act2 + (size_t)(tm * 32 + lrow) * 2304 + khalf * 1152 + kh * 16;
    const signed char* bptr = wf1s + (size_t)(tn * 64 + lrow) * 2304 + khalf * 1152 + kh * 16;

    i32x16 acc0 = {0};
    i32x16 acc1 = {0};
#pragma unroll 6
    for (int ks = 0; ks < 36; ++ks) {
        i32x4 a  = *(const i32x4*)(aptr + ks * 32);
        i32x4 b0 = *(const i32x4*)(bptr + ks * 32);
        i32x4 b1 = *(const i32x4*)(bptr + 32 * 2304 + ks * 32);
        acc0 = __builtin_amdgcn_mfma_i32_32x32x32_i8(a, b0, acc0, 0, 0, 0);
        acc1 = __builtin_amdgcn_mfma_i32_32x32x32_i8(a, b1, acc1, 0, 0, 0);
    }
    if (khalf) {
        int* rp = &red[tile_local][0];
#pragma unroll
        for (int r = 0; r < 16; r++) rp[r * 64 + l] = acc0[r];
#pragma unroll
        for (int r = 0; r < 16; r++) rp[(r + 16) * 64 + l] = acc1[r];
    }
    __syncthreads();
    if (!khalf) {
        const int* rp = &red[tile_local][0];
#pragma unroll
        for (int r = 0; r < 16; r++) acc0[r] += rp[r * 64 + l];
#pragma unroll
        for (int r = 0; r < 16; r++) acc1[r] += rp[(r + 16) * 64 + l];

        int col0 = tn * 64 + lrow;
        int col1 = col0 + 32;
        float bi0 = bf1[col0], m0 = mf1[col0];
        float sc0 = gf1[col0] / sqrtf(vf1[col0] + 1e-5f), bb0 = bef1[col0];
        float bi1 = bf1[col1], m1 = mf1[col1];
        float sc1 = gf1[col1] / sqrtf(vf1[col1] + 1e-5f), bb1 = bef1[col1];
#pragma unroll
        for (int r = 0; r < 16; r++) {
            int row = tm * 32 + (r & 3) + 8 * (r >> 2) + 4 * kh;
            float bn0 = ((float)acc0[r] + bi0 - m0) * sc0 + bb0;
            float bn1 = ((float)acc1[r] + bi1 - m1) * sc1 + bb1;
            act3[(size_t)row * 1024 + col0] = (signed char)fsign(bn0);
            act3[(size_t)row * 1024 + col1] = (signed char)fsign(bn1);
        }
    }
}

// K4: fc2 (1024->10) + bias + BN + log_softmax. One wave per image.
__global__ void k4_fc2(const signed char* __restrict__ act3, const signed char* __restrict__ swf2,
                       const float* __restrict__ bf2, const float* __restrict__ gf2,
                       const float* __restrict__ bef2, const float* __restrict__ mf2,
                       const float* __restrict__ vf2, float* __restrict__ out) {
    int wid = (blockIdx.x * 256 + threadIdx.x) >> 6;
    int lane = threadIdx.x & 63;
    if (wid >= BATCH) return;
    const int* hd = (const int*)act3 + (size_t)wid * 256;
    const int* wd = (const int*)swf2;
    int acc[10];
#pragma unroll
    for (int o = 0; o < 10; o++) acc[o] = 0;
#pragma unroll
    for (int i = 0; i < 4; i++) {
        int k4 = i * 64 + lane;
        int hv = hd[k4];
#pragma unroll
        for (int o = 0; o < 10; o++)
            acc[o] = sdot4(hv, wd[o * 256 + k4], acc[o]);
    }
#pragma unroll
    for (int o = 0; o < 10; o++)
#pragma unroll
        for (int s = 32; s > 0; s >>= 1) acc[o] += __shfl_xor(acc[o], s);
    if (lane == 0) {
        float logit[10];
        float mx = -1e30f;
#pragma unroll
        for (int o = 0; o < 10; o++) {
            float z = (float)acc[o] + bf2[o];
            float bn = (z - mf2[o]) * (gf2[o] / sqrtf(vf2[o] + 1e-5f)) + bef2[o];
            logit[o] = bn;
            mx = fmaxf(mx, bn);
        }
        float s = 0.f;
#pragma unroll
        for (int o = 0; o < 10; o++) s += expf(logit[o] - mx);
        float lse = mx + logf(s);
#pragma unroll
        for (int o = 0; o < 10; o++) out[(size_t)wid * 10 + o] = logit[o] - lse;
    }
}

extern "C" void kernel_launch(void* const* d_in, const int* in_sizes, int n_in,
                              void* d_out, int out_size, void* d_ws, size_t ws_size,
                              hipStream_t stream) {
    const float* x   = (const float*)d_in[0];
    const float* w1  = (const float*)d_in[1];
    const float* b1  = (const float*)d_in[2];
    const float* g1  = (const float*)d_in[3];
    const float* be1 = (const float*)d_in[4];
    const float* m1  = (const float*)d_in[5];
    const float* v1  = (const float*)d_in[6];
    const float* w2  = (const float*)d_in[7];
    const float* b2  = (const float*)d_in[8];
    const float* g2  = (const float*)d_in[9];
    const float* be2 = (const float*)d_in[10];
    const float* m2  = (const float*)d_in[11];
    const float* v2  = (const float*)d_in[12];
    const float* wf1 = (const float*)d_in[13];
    const float* bf1 = (const float*)d_in[14];
    const float* gf1 = (const float*)d_in[15];
    const float* bef1= (const float*)d_in[16];
    const float* mf1 = (const float*)d_in[17];
    const float* vf1 = (const float*)d_in[18];
    const float* wf2 = (const float*)d_in[19];
    const float* bf2 = (const float*)d_in[20];
    const float* gf2 = (const float*)d_in[21];
    const float* bef2= (const float*)d_in[22];
    const float* mf2 = (const float*)d_in[23];
    const float* vf2 = (const float*)d_in[24];
    float* out = (float*)d_out;

    // ws layout (all int8 unless noted)
    char* ws = (char*)d_ws;
    signed char* act1 = (signed char*)ws;                  // 2048*169*32   = 11,075,584
    signed char* act2 = act1 + 11075584;                   // 2048*2304     =  4,718,592
    signed char* act3 = act2 + 4718592;                    // 2048*1024     =  2,097,152
    signed char* w2p  = act3 + 2097152;                    // 64*25*32      =     51,200
    signed char* wf1s = w2p + 51200;                       // 1024*2304     =  2,359,296
    signed char* wf2p = wf1s + 2359296;                    // 10*1024       =     10,240
    float* k1c = (float*)(wf2p + 10240);                   // 32*16 floats  =      2,048 B

    // fused prep: 2,359,296 + 51,200 + 10,240 + 416 = 2,421,152 elems
    prep_all<<<9458, 256, 0, stream>>>(w1, b1, g1, be1, m1, v1, w2, wf1, wf2,
                                       w2p, wf1s, wf2p, k1c);

    k1_conv1<<<2048, 256, 0, stream>>>(x, k1c, act1);

    k2_mfma<<<1024, 576, 0, stream>>>(act1, w2p, b2, g2, be2, m2, v2, act2);

    k3_mfma<<<512, 256, 0, stream>>>(act2, wf1s, bf1, gf1, bef1, mf1, vf1, act3);

    k4_fc2<<<512, 256, 0, stream>>>(act3, wf2p, bf2, gf2, bef2, mf2, vf2, out);
}

// Round 10
// 84.504 us; speedup vs baseline: 1.6750x; 1.1944x over previous
//
#include <hip/hip_runtime.h>
#include <math.h>

#define BATCH 2048

typedef __attribute__((ext_vector_type(4))) int i32x4;
typedef __attribute__((ext_vector_type(16))) int i32x16;

__device__ __forceinline__ int sdot4(int a, int b, int c) {
    return __builtin_amdgcn_sdot4(a, b, c, false);
}

__device__ __forceinline__ float fsign(float v) {
    return v > 0.f ? 1.f : (v < 0.f ? -1.f : 0.f);
}

// One fused prep kernel: wf1 binarize | w2 pack | wf2 binarize | k1 const table
__global__ void prep_all(const float* __restrict__ w1, const float* __restrict__ b1,
                         const float* __restrict__ g1, const float* __restrict__ be1,
                         const float* __restrict__ m1, const float* __restrict__ v1,
                         const float* __restrict__ w2, const float* __restrict__ wf1,
                         const float* __restrict__ wf2,
                         signed char* __restrict__ w2p, signed char* __restrict__ wf1s,
                         signed char* __restrict__ wf2p, float* __restrict__ k1c) {
    int i = blockIdx.x * 256 + threadIdx.x;
    if (i < 2359296) {  // wf1 sign (natural [1024][2304] layout)
        float v = wf1[i];
        wf1s[i] = v > 0.f ? 1 : (v < 0.f ? -1 : 0);
        return;
    }
    i -= 2359296;
    if (i < 51200) {    // w2 [64][32][5][5] -> w2p [64][25][32]
        int ic = i % 32, tap = (i / 32) % 25, oc = i / 800;
        float v = w2[(oc * 32 + ic) * 25 + tap];
        w2p[i] = v > 0.f ? 1 : (v < 0.f ? -1 : 0);
        return;
    }
    i -= 51200;
    if (i < 10240) {    // wf2 sign
        float v = wf2[i];
        wf2p[i] = v > 0.f ? 1 : (v < 0.f ? -1 : 0);
        return;
    }
    i -= 10240;
    if (i < 416) {      // k1c [32][16] = {sw0..8, bias, m, sc, bb}
        int oc = i / 13, s = i - oc * 13;
        float r;
        if (s < 9) r = fsign(w1[oc * 9 + s]);
        else if (s == 9) r = b1[oc];
        else if (s == 10) r = m1[oc];
        else if (s == 11) r = g1[oc] / sqrtf(v1[oc] + 1e-5f);
        else r = be1[oc];
        k1c[oc * 16 + s] = r;
    }
}

// K1: conv1 + bias + BN + sign + pool2 -> act1 channel-last [B][13][13][32] int8
// Block = one image (x staged in LDS). lane oc = tid&31 (consts in VGPRs),
// cell-group g = tid>>5 walks cells g, g+8, g+16, ...
__global__ __launch_bounds__(256) void k1_conv1(
        const float* __restrict__ x, const float* __restrict__ k1c,
        signed char* __restrict__ act1) {
    __shared__ __align__(16) float xs[784];
    int b = blockIdx.x, tid = threadIdx.x;
    if (tid < 196) ((float4*)xs)[tid] = ((const float4*)(x + (size_t)b * 784))[tid];
    __syncthreads();

    int oc = tid & 31, g = tid >> 5;
    const float* c = k1c + oc * 16;
    float sw[9];
#pragma unroll
    for (int i = 0; i < 9; i++) sw[i] = c[i];
    float bias = c[9], m = c[10], sc = c[11], bb = c[12];
    signed char* dst = act1 + (size_t)b * 5408 + oc;

    for (int i = 0; i < 22; i++) {
        int cell = i * 8 + g;
        if (cell < 169) {
            int py = cell / 13, px = cell - py * 13;
            const float* wnd = xs + py * 56 + px * 2;  // (2py)*28 + 2px, even idx
            float xr[4][4];
#pragma unroll
            for (int dy = 0; dy < 4; dy++) {
                float2 lo = *(const float2*)(wnd + dy * 28);
                float2 hi = *(const float2*)(wnd + dy * 28 + 2);
                xr[dy][0] = lo.x; xr[dy][1] = lo.y;
                xr[dy][2] = hi.x; xr[dy][3] = hi.y;
            }
            float maxacc = -1e30f;
#pragma unroll
            for (int q = 0; q < 4; q++) {
                int dyp = q >> 1, dxp = q & 1;
                float acc = 0.f;
#pragma unroll
                for (int ky = 0; ky < 3; ky++)
#pragma unroll
                    for (int kx = 0; kx < 3; kx++)
                        acc += xr[dyp + ky][dxp + kx] * sw[ky * 3 + kx];
                maxacc = fmaxf(maxacc, acc);   // BN monotone (sc>0): max commutes
            }
            float bn = (maxacc + bias - m) * sc + bb;  // same assoc as before
            dst[(size_t)cell * 32] = (signed char)fsign(bn);
        }
    }
}

// K2: conv2 as implicit-GEMM MFMA i8. Block = 2 images, 9 waves.
#define K2_IMG_STRIDE 9248          // 17*17*32
#define K2_WOFF 18496               // 2*9248
__device__ __forceinline__ void k2_epilogue(i32x16 A, int oc, int wave, int kh, int b0,
                                            const float* __restrict__ b2,
                                            const float* __restrict__ g2,
                                            const float* __restrict__ be2,
                                            const float* __restrict__ m2,
                                            const float* __restrict__ v2,
                                            signed char* __restrict__ act2) {
    float bias = b2[oc], mm = m2[oc];
    float sc = g2[oc] / sqrtf(v2[oc] + 1e-5f), bb = be2[oc];
#pragma unroll
    for (int g = 0; g < 4; g++) {
        int qo = wave * 8 + kh + 2 * g;      // 0..71 pool cell (2 images)
        int imo = qo / 36, qqo = qo - imo * 36;
        float best = -2.f;
#pragma unroll
        for (int jj = 0; jj < 4; jj++) {     // 4 pool partners live in reg quad
            float z = (float)A[g * 4 + jj] + bias;
            float bn = (z - mm) * sc + bb;
            best = fmaxf(best, fsign(bn));
        }
        act2[((size_t)(b0 + imo) * 64 + oc) * 36 + qqo] = (signed char)best;
    }
}

__global__ __launch_bounds__(576) void k2_mfma(
        const signed char* __restrict__ act1, const signed char* __restrict__ w2p,
        const float* __restrict__ b2, const float* __restrict__ g2,
        const float* __restrict__ be2, const float* __restrict__ m2,
        const float* __restrict__ v2, signed char* __restrict__ act2) {
    __shared__ __align__(16) signed char smem[69696];  // 18496 + 51200
    int tid = threadIdx.x;
    int b0 = blockIdx.x * 2;
    i32x4* s4 = (i32x4*)smem;
    i32x4 z4 = {0, 0, 0, 0};
    for (int i = tid; i < 1156; i += 576) s4[i] = z4;
    __syncthreads();
    {
        const i32x4* src = (const i32x4*)(act1 + (size_t)b0 * 5408);
        for (int i = tid; i < 676; i += 576) {
            int im = i / 338, r = i - im * 338;
            int pix = r >> 1, half = r & 1;
            int yy = pix / 13 + 2, xx = pix % 13 + 2;
            *(i32x4*)(smem + im * K2_IMG_STRIDE + (yy * 17 + xx) * 32 + half * 16) = src[i];
        }
        const i32x4* wsrc = (const i32x4*)w2p;
        for (int i = tid; i < 3200; i += 576) {
            int oc = i / 50, r = i - oc * 50;
            int tap = r >> 1, half = r & 1;
            *(i32x4*)(smem + K2_WOFF + tap * 2048 + oc * 32 + half * 16) = wsrc[i];
        }
    }
    __syncthreads();

    int wave = tid >> 6, lane = tid & 63;
    int lrow = lane & 31, kh = lane >> 5;
    int m = wave * 32 + lrow;
    int q = m >> 2, j = m & 3;
    int img = q / 36, qq = q - img * 36;
    int oy = 2 * (qq / 6) + (j >> 1);
    int ox = 2 * (qq - (qq / 6) * 6) + (j & 1);
    const signed char* abase = smem + img * K2_IMG_STRIDE + (oy * 17 + ox) * 32 + kh * 16;
    const signed char* bbase = smem + K2_WOFF + lrow * 32 + kh * 16;

    i32x16 acc0 = {0};
    i32x16 acc1 = {0};
#pragma unroll 5
    for (int tap = 0; tap < 25; ++tap) {
        int ky = tap / 5, kx = tap - (tap / 5) * 5;
        i32x4 a = *(const i32x4*)(abase + (ky * 17 + kx) * 32);
        i32x4 w0 = *(const i32x4*)(bbase + tap * 2048);
        i32x4 w1 = *(const i32x4*)(bbase + tap * 2048 + 1024);
        acc0 = __builtin_amdgcn_mfma_i32_32x32x32_i8(a, w0, acc0, 0, 0, 0);
        acc1 = __builtin_amdgcn_mfma_i32_32x32x32_i8(a, w1, acc1, 0, 0, 0);
    }
    k2_epilogue(acc0, lrow,      wave, kh, b0, b2, g2, be2, m2, v2, act2);
    k2_epilogue(acc1, 32 + lrow, wave, kh, b0, b2, g2, be2, m2, v2, act2);
}

// K3: fc1 as LDS-tiled MFMA i8 GEMM 2048x1024x2304.
// Tile 128x128, 8 waves (wave tile 32x64), BK=128 (18 steps), reg-staged prefetch.
// LDS seg-major, padded seg stride 2064 B: conflict-free ds_write, 4-way-floor ds_read.
#define K3_SEG 2064                 // 128*16 + 16 pad
#define K3_BOFF 16512               // 8 * 2064
__global__ __launch_bounds__(512) void k3_mfma(
        const signed char* __restrict__ act2, const signed char* __restrict__ wf1s,
        const float* __restrict__ bf1, const float* __restrict__ gf1,
        const float* __restrict__ bef1, const float* __restrict__ mf1,
        const float* __restrict__ vf1, signed char* __restrict__ act3) {
    __shared__ __align__(16) signed char s[2 * K3_BOFF];  // 33024
    int tid = threadIdx.x;
    int bid = blockIdx.x;
    int tn = bid & 7, tm = bid >> 3;   // tn <-> XCD: B panel L2-resident per XCD

    // staging: entries e=tid (rows 0..63) and e=tid+512 (rows 64..127); seg = e&7
    int r0 = tid >> 3, sg = tid & 7;
    int r1 = r0 + 64;
    const signed char* Ab = act2 + (size_t)tm * 128 * 2304;
    const signed char* Bb = wf1s + (size_t)tn * 128 * 2304;
    size_t g0 = (size_t)r0 * 2304 + sg * 16;
    size_t g1 = (size_t)r1 * 2304 + sg * 16;
    int lw0 = sg * K3_SEG + r0 * 16;   // LDS write addrs (conflict-free: 8 segs/8 banks)
    int lw1 = sg * K3_SEG + r1 * 16;

    i32x4 ra0 = *(const i32x4*)(Ab + g0);
    i32x4 ra1 = *(const i32x4*)(Ab + g1);
    i32x4 rb0 = *(const i32x4*)(Bb + g0);
    i32x4 rb1 = *(const i32x4*)(Bb + g1);

    int l = tid & 63, wid = tid >> 6;
    int wr = wid >> 1, wn = wid & 1;   // wave tile: rows wr*32, cols wn*64
    int lrow = l & 31, kh = l >> 5;
    int raddrA = kh * K3_SEG + (wr * 32 + lrow) * 16;            // + ks*2*K3_SEG
    int raddrB0 = K3_BOFF + kh * K3_SEG + (wn * 64 + lrow) * 16;
    int raddrB1 = raddrB0 + 32 * 16;

    i32x16 acc0 = {0};
    i32x16 acc1 = {0};
    for (int t = 0; t < 18; ++t) {
        if (t) __syncthreads();
        *(i32x4*)(s + lw0) = ra0;
        *(i32x4*)(s + lw1) = ra1;
        *(i32x4*)(s + K3_BOFF + lw0) = rb0;
        *(i32x4*)(s + K3_BOFF + lw1) = rb1;
        if (t < 17) {                  // prefetch next K-chunk; latency hides under MFMA
            size_t ko = (size_t)(t + 1) * 128;
            ra0 = *(const i32x4*)(Ab + g0 + ko);
            ra1 = *(const i32x4*)(Ab + g1 + ko);
            rb0 = *(const i32x4*)(Bb + g0 + ko);
            rb1 = *(const i32x4*)(Bb + g1 + ko);
        }
        __syncthreads();
#pragma unroll
        for (int ks = 0; ks < 4; ++ks) {
            i32x4 a  = *(const i32x4*)(s + raddrA + ks * 2 * K3_SEG);
            i32x4 b0 = *(const i32x4*)(s + raddrB0 + ks * 2 * K3_SEG);
            i32x4 b1 = *(const i32x4*)(s + raddrB1 + ks * 2 * K3_SEG);
            acc0 = __builtin_amdgcn_mfma_i32_32x32x32_i8(a, b0, acc0, 0, 0, 0);
            acc1 = __builtin_amdgcn_mfma_i32_32x32x32_i8(a, b1, acc1, 0, 0, 0);
        }
    }

    int col0 = tn * 128 + wn * 64 + lrow;
    int col1 = col0 + 32;
    float bi0 = bf1[col0], m0 = mf1[col0];
    float sc0 = gf1[col0] / sqrtf(vf1[col0] + 1e-5f), bb0 = bef1[col0];
    float bi1 = bf1[col1], m1 = mf1[col1];
    float sc1 = gf1[col1] / sqrtf(vf1[col1] + 1e-5f), bb1 = bef1[col1];
#pragma unroll
    for (int r = 0; r < 16; r++) {
        int row = tm * 128 + wr * 32 + (r & 3) + 8 * (r >> 2) + 4 * kh;
        float bn0 = ((float)acc0[r] + bi0 - m0) * sc0 + bb0;
        float bn1 = ((float)acc1[r] + bi1 - m1) * sc1 + bb1;
        act3[(size_t)row * 1024 + col0] = (signed char)fsign(bn0);
        act3[(size_t)row * 1024 + col1] = (signed char)fsign(bn1);
    }
}

// K4: fc2 (1024->10) + bias + BN + log_softmax. One wave per image.
__global__ void k4_fc2(const signed char* __restrict__ act3, const signed char* __restrict__ swf2,
                       const float* __restrict__ bf2, const float* __restrict__ gf2,
                       const float* __restrict__ bef2, const float* __restrict__ mf2,
                       const float* __restrict__ vf2, float* __restrict__ out) {
    int wid = (blockIdx.x * 256 + threadIdx.x) >> 6;
    int lane = threadIdx.x & 63;
    if (wid >= BATCH) return;
    const int* hd = (const int*)act3 + (size_t)wid * 256;
    const int* wd = (const int*)swf2;
    int acc[10];
#pragma unroll
    for (int o = 0; o < 10; o++) acc[o] = 0;
#pragma unroll
    for (int i = 0; i < 4; i++) {
        int k4 = i * 64 + lane;
        int hv = hd[k4];
#pragma unroll
        for (int o = 0; o < 10; o++)
            acc[o] = sdot4(hv, wd[o * 256 + k4], acc[o]);
    }
#pragma unroll
    for (int o = 0; o < 10; o++)
#pragma unroll
        for (int s = 32; s > 0; s >>= 1) acc[o] += __shfl_xor(acc[o], s);
    if (lane == 0) {
        float logit[10];
        float mx = -1e30f;
#pragma unroll
        for (int o = 0; o < 10; o++) {
            float z = (float)acc[o] + bf2[o];
            float bn = (z - mf2[o]) * (gf2[o] / sqrtf(vf2[o] + 1e-5f)) + bef2[o];
            logit[o] = bn;
            mx = fmaxf(mx, bn);
        }
        float s = 0.f;
#pragma unroll
        for (int o = 0; o < 10; o++) s += expf(logit[o] - mx);
        float lse = mx + logf(s);
#pragma unroll
        for (int o = 0; o < 10; o++) out[(size_t)wid * 10 + o] = logit[o] - lse;
    }
}

extern "C" void kernel_launch(void* const* d_in, const int* in_sizes, int n_in,
                              void* d_out, int out_size, void* d_ws, size_t ws_size,
                              hipStream_t stream) {
    const float* x   = (const float*)d_in[0];
    const float* w1  = (const float*)d_in[1];
    const float* b1  = (const float*)d_in[2];
    const float* g1  = (const float*)d_in[3];
    const float* be1 = (const float*)d_in[4];
    const float* m1  = (const float*)d_in[5];
    const float* v1  = (const float*)d_in[6];
    const float* w2  = (const float*)d_in[7];
    const float* b2  = (const float*)d_in[8];
    const float* g2  = (const float*)d_in[9];
    const float* be2 = (const float*)d_in[10];
    const float* m2  = (const float*)d_in[11];
    const float* v2  = (const float*)d_in[12];
    const float* wf1 = (const float*)d_in[13];
    const float* bf1 = (const float*)d_in[14];
    const float* gf1 = (const float*)d_in[15];
    const float* bef1= (const float*)d_in[16];
    const float* mf1 = (const float*)d_in[17];
    const float* vf1 = (const float*)d_in[18];
    const float* wf2 = (const float*)d_in[19];
    const float* bf2 = (const float*)d_in[20];
    const float* gf2 = (const float*)d_in[21];
    const float* bef2= (const float*)d_in[22];
    const float* mf2 = (const float*)d_in[23];
    const float* vf2 = (const float*)d_in[24];
    float* out = (float*)d_out;

    // ws layout (all int8 unless noted)
    char* ws = (char*)d_ws;
    signed char* act1 = (signed char*)ws;                  // 2048*169*32   = 11,075,584
    signed char* act2 = act1 + 11075584;                   // 2048*2304     =  4,718,592
    signed char* act3 = act2 + 4718592;                    // 2048*1024     =  2,097,152
    signed char* w2p  = act3 + 2097152;                    // 64*25*32      =     51,200
    signed char* wf1s = w2p + 51200;                       // 1024*2304     =  2,359,296
    signed char* wf2p = wf1s + 2359296;                    // 10*1024       =     10,240
    float* k1c = (float*)(wf2p + 10240);                   // 32*16 floats  =      2,048 B

    // fused prep: 2,359,296 + 51,200 + 10,240 + 416 = 2,421,152 elems
    prep_all<<<9458, 256, 0, stream>>>(w1, b1, g1, be1, m1, v1, w2, wf1, wf2,
                                       w2p, wf1s, wf2p, k1c);

    k1_conv1<<<2048, 256, 0, stream>>>(x, k1c, act1);

    k2_mfma<<<1024, 576, 0, stream>>>(act1, w2p, b2, g2, be2, m2, v2, act2);

    k3_mfma<<<128, 512, 0, stream>>>(act2, wf1s, bf1, gf1, bef1, mf1, vf1, act3);

    k4_fc2<<<512, 256, 0, stream>>>(act3, wf2p, bf2, gf2, bef2, mf2, vf2, out);
}

// Round 11
// 82.979 us; speedup vs baseline: 1.7058x; 1.0184x over previous
//
#include <hip/hip_runtime.h>
#include <math.h>

#define BATCH 2048

typedef __attribute__((ext_vector_type(4))) int i32x4;
typedef __attribute__((ext_vector_type(16))) int i32x16;

__device__ __forceinline__ int sdot4(int a, int b, int c) {
    return __builtin_amdgcn_sdot4(a, b, c, false);
}

__device__ __forceinline__ float fsign(float v) {
    return v > 0.f ? 1.f : (v < 0.f ? -1.f : 0.f);
}

// One fused prep kernel: wf1 binarize | w2 pack | wf2 binarize | k1 const table
__global__ void prep_all(const float* __restrict__ w1, const float* __restrict__ b1,
                         const float* __restrict__ g1, const float* __restrict__ be1,
                         const float* __restrict__ m1, const float* __restrict__ v1,
                         const float* __restrict__ w2, const float* __restrict__ wf1,
                         const float* __restrict__ wf2,
                         signed char* __restrict__ w2p, signed char* __restrict__ wf1s,
                         signed char* __restrict__ wf2p, float* __restrict__ k1c) {
    int i = blockIdx.x * 256 + threadIdx.x;
    if (i < 2359296) {  // wf1 sign (natural [1024][2304] layout)
        float v = wf1[i];
        wf1s[i] = v > 0.f ? 1 : (v < 0.f ? -1 : 0);
        return;
    }
    i -= 2359296;
    if (i < 51200) {    // w2 [64][32][5][5] -> w2p [64][25][32]
        int ic = i % 32, tap = (i / 32) % 25, oc = i / 800;
        float v = w2[(oc * 32 + ic) * 25 + tap];
        w2p[i] = v > 0.f ? 1 : (v < 0.f ? -1 : 0);
        return;
    }
    i -= 51200;
    if (i < 10240) {    // wf2 sign
        float v = wf2[i];
        wf2p[i] = v > 0.f ? 1 : (v < 0.f ? -1 : 0);
        return;
    }
    i -= 10240;
    if (i < 416) {      // k1c [32][16] = {sw0..8, bias, m, sc, bb}
        int oc = i / 13, s = i - oc * 13;
        float r;
        if (s < 9) r = fsign(w1[oc * 9 + s]);
        else if (s == 9) r = b1[oc];
        else if (s == 10) r = m1[oc];
        else if (s == 11) r = g1[oc] / sqrtf(v1[oc] + 1e-5f);
        else r = be1[oc];
        k1c[oc * 16 + s] = r;
    }
}

// K1: conv1 + bias + BN + sign + pool2 -> act1 channel-last [B][13][13][32] int8
// Block = one image in LDS, plus a 2-float-shifted copy so every 4-col window
// row is ONE aligned ds_read_b128 (even px from xs, odd px from xs2).
__global__ __launch_bounds__(256) void k1_conv1(
        const float* __restrict__ x, const float* __restrict__ k1c,
        signed char* __restrict__ act1) {
    __shared__ __align__(16) float xs[784];
    __shared__ __align__(16) float xs2[784];   // xs2[i] = xs[i+2]
    int b = blockIdx.x, tid = threadIdx.x;
    if (tid < 196) ((float4*)xs)[tid] = ((const float4*)(x + (size_t)b * 784))[tid];
    __syncthreads();
    for (int j = tid; j < 782; j += 256) xs2[j] = xs[j + 2];
    __syncthreads();

    int oc = tid & 31, g = tid >> 5;
    const float* c = k1c + oc * 16;
    float sw[9];
#pragma unroll
    for (int i = 0; i < 9; i++) sw[i] = c[i];
    float bias = c[9], m = c[10], sc = c[11], bb = c[12];
    signed char* dst = act1 + (size_t)b * 5408 + oc;

    for (int i = 0; i < 22; i++) {
        int cell = i * 8 + g;
        if (cell < 169) {
            int py = cell / 13, px = cell - py * 13;
            const float* wnd = (px & 1) ? (xs2 + py * 56 + px * 2 - 2)
                                        : (xs + py * 56 + px * 2);
            float xr[4][4];
#pragma unroll
            for (int dy = 0; dy < 4; dy++) {
                float4 rv = *(const float4*)(wnd + dy * 28);   // aligned b128
                xr[dy][0] = rv.x; xr[dy][1] = rv.y;
                xr[dy][2] = rv.z; xr[dy][3] = rv.w;
            }
            float maxacc = -1e30f;
#pragma unroll
            for (int q = 0; q < 4; q++) {
                int dyp = q >> 1, dxp = q & 1;
                float acc = 0.f;
#pragma unroll
                for (int ky = 0; ky < 3; ky++)
#pragma unroll
                    for (int kx = 0; kx < 3; kx++)
                        acc += xr[dyp + ky][dxp + kx] * sw[ky * 3 + kx];
                maxacc = fmaxf(maxacc, acc);   // BN monotone (sc>0): max commutes
            }
            float bn = (maxacc + bias - m) * sc + bb;  // same assoc as before
            dst[(size_t)cell * 32] = (signed char)fsign(bn);
        }
    }
}

// K2: conv2 as implicit-GEMM MFMA i8. Block = 2 images, 9 waves.
#define K2_IMG_STRIDE 9248          // 17*17*32
#define K2_WOFF 18496               // 2*9248
__device__ __forceinline__ void k2_epilogue(i32x16 A, int oc, int wave, int kh, int b0,
                                            const float* __restrict__ b2,
                                            const float* __restrict__ g2,
                                            const float* __restrict__ be2,
                                            const float* __restrict__ m2,
                                            const float* __restrict__ v2,
                                            signed char* __restrict__ act2) {
    float bias = b2[oc], mm = m2[oc];
    float sc = g2[oc] / sqrtf(v2[oc] + 1e-5f), bb = be2[oc];
#pragma unroll
    for (int g = 0; g < 4; g++) {
        int qo = wave * 8 + kh + 2 * g;      // 0..71 pool cell (2 images)
        int imo = qo / 36, qqo = qo - imo * 36;
        float best = -2.f;
#pragma unroll
        for (int jj = 0; jj < 4; jj++) {     // 4 pool partners live in reg quad
            float z = (float)A[g * 4 + jj] + bias;
            float bn = (z - mm) * sc + bb;
            best = fmaxf(best, fsign(bn));
        }
        act2[((size_t)(b0 + imo) * 64 + oc) * 36 + qqo] = (signed char)best;
    }
}

__global__ __launch_bounds__(576) void k2_mfma(
        const signed char* __restrict__ act1, const signed char* __restrict__ w2p,
        const float* __restrict__ b2, const float* __restrict__ g2,
        const float* __restrict__ be2, const float* __restrict__ m2,
        const float* __restrict__ v2, signed char* __restrict__ act2) {
    __shared__ __align__(16) signed char smem[69696];  // 18496 + 51200
    int tid = threadIdx.x;
    int b0 = blockIdx.x * 2;
    i32x4* s4 = (i32x4*)smem;
    i32x4 z4 = {0, 0, 0, 0};
    for (int i = tid; i < 1156; i += 576) s4[i] = z4;
    __syncthreads();
    {
        const i32x4* src = (const i32x4*)(act1 + (size_t)b0 * 5408);
        for (int i = tid; i < 676; i += 576) {
            int im = i / 338, r = i - im * 338;
            int pix = r >> 1, half = r & 1;
            int yy = pix / 13 + 2, xx = pix % 13 + 2;
            *(i32x4*)(smem + im * K2_IMG_STRIDE + (yy * 17 + xx) * 32 + half * 16) = src[i];
        }
        const i32x4* wsrc = (const i32x4*)w2p;
        for (int i = tid; i < 3200; i += 576) {
            int oc = i / 50, r = i - oc * 50;
            int tap = r >> 1, half = r & 1;
            *(i32x4*)(smem + K2_WOFF + tap * 2048 + oc * 32 + half * 16) = wsrc[i];
        }
    }
    __syncthreads();

    int wave = tid >> 6, lane = tid & 63;
    int lrow = lane & 31, kh = lane >> 5;
    int m = wave * 32 + lrow;
    int q = m >> 2, j = m & 3;
    int img = q / 36, qq = q - img * 36;
    int oy = 2 * (qq / 6) + (j >> 1);
    int ox = 2 * (qq - (qq / 6) * 6) + (j & 1);
    const signed char* abase = smem + img * K2_IMG_STRIDE + (oy * 17 + ox) * 32 + kh * 16;
    const signed char* bbase = smem + K2_WOFF + lrow * 32 + kh * 16;

    i32x16 acc0 = {0};
    i32x16 acc1 = {0};
#pragma unroll 5
    for (int tap = 0; tap < 25; ++tap) {
        int ky = tap / 5, kx = tap - (tap / 5) * 5;
        i32x4 a = *(const i32x4*)(abase + (ky * 17 + kx) * 32);
        i32x4 w0 = *(const i32x4*)(bbase + tap * 2048);
        i32x4 w1 = *(const i32x4*)(bbase + tap * 2048 + 1024);
        acc0 = __builtin_amdgcn_mfma_i32_32x32x32_i8(a, w0, acc0, 0, 0, 0);
        acc1 = __builtin_amdgcn_mfma_i32_32x32x32_i8(a, w1, acc1, 0, 0, 0);
    }
    k2_epilogue(acc0, lrow,      wave, kh, b0, b2, g2, be2, m2, v2, act2);
    k2_epilogue(acc1, 32 + lrow, wave, kh, b0, b2, g2, be2, m2, v2, act2);
}

// K3: fc1 as LDS-tiled MFMA i8 GEMM 2048x1024x2304.
// Tile 128Mx64N, 4 waves (wave tile 32x64), BK=128 (18 steps), reg-staged prefetch.
// Grid 256 blocks -> every CU busy (the 128-block version idled half the GPU).
#define K3A_SEG 2064                // 128*16 + 16 pad
#define K3B_SEG 1040                // 64*16 + 16 pad
#define K3_BOFF 16512               // 8 * 2064
__global__ __launch_bounds__(256) void k3_mfma(
        const signed char* __restrict__ act2, const signed char* __restrict__ wf1s,
        const float* __restrict__ bf1, const float* __restrict__ gf1,
        const float* __restrict__ bef1, const float* __restrict__ mf1,
        const float* __restrict__ vf1, signed char* __restrict__ act3) {
    __shared__ __align__(16) signed char s[K3_BOFF + 8 * K3B_SEG];  // 24832
    int tid = threadIdx.x;
    int bid = blockIdx.x;
    int tn = bid & 15, tm = bid >> 4;   // bid%8 ~ XCD: same-XCD blocks share B panels

    const signed char* Ab = act2 + (size_t)tm * 128 * 2304;
    const signed char* Bb = wf1s + (size_t)tn * 64 * 2304;
    // staging, bank-swizzled: entry e -> row=e>>3, sg=(e+(e>>3))&7
    size_t gA[4]; int lwA[4];
#pragma unroll
    for (int i = 0; i < 4; i++) {
        int e = tid + 256 * i, row = e >> 3, sg = (e + row) & 7;
        gA[i] = (size_t)row * 2304 + sg * 16;
        lwA[i] = sg * K3A_SEG + row * 16;
    }
    size_t gB[2]; int lwB[2];
#pragma unroll
    for (int i = 0; i < 2; i++) {
        int e = tid + 256 * i, row = e >> 3, sg = (e + row) & 7;
        gB[i] = (size_t)row * 2304 + sg * 16;
        lwB[i] = K3_BOFF + sg * K3B_SEG + row * 16;
    }

    i32x4 ra[4], rb[2];
#pragma unroll
    for (int i = 0; i < 4; i++) ra[i] = *(const i32x4*)(Ab + gA[i]);
#pragma unroll
    for (int i = 0; i < 2; i++) rb[i] = *(const i32x4*)(Bb + gB[i]);

    int l = tid & 63, wid = tid >> 6;          // wid = M-subtile (4 waves)
    int lrow = l & 31, kh = l >> 5;
    int raddrA = kh * K3A_SEG + (wid * 32 + lrow) * 16;
    int raddrB0 = K3_BOFF + kh * K3B_SEG + lrow * 16;
    int raddrB1 = raddrB0 + 32 * 16;

    i32x16 acc0 = {0};
    i32x16 acc1 = {0};
    for (int t = 0; t < 18; ++t) {
        if (t) __syncthreads();
#pragma unroll
        for (int i = 0; i < 4; i++) *(i32x4*)(s + lwA[i]) = ra[i];
#pragma unroll
        for (int i = 0; i < 2; i++) *(i32x4*)(s + lwB[i]) = rb[i];
        if (t < 17) {                  // prefetch next K-chunk under MFMA
            size_t ko = (size_t)(t + 1) * 128;
#pragma unroll
            for (int i = 0; i < 4; i++) ra[i] = *(const i32x4*)(Ab + gA[i] + ko);
#pragma unroll
            for (int i = 0; i < 2; i++) rb[i] = *(const i32x4*)(Bb + gB[i] + ko);
        }
        __syncthreads();
#pragma unroll
        for (int ks = 0; ks < 4; ++ks) {
            i32x4 a  = *(const i32x4*)(s + raddrA + ks * 2 * K3A_SEG);
            i32x4 b0 = *(const i32x4*)(s + raddrB0 + ks * 2 * K3B_SEG);
            i32x4 b1 = *(const i32x4*)(s + raddrB1 + ks * 2 * K3B_SEG);
            acc0 = __builtin_amdgcn_mfma_i32_32x32x32_i8(a, b0, acc0, 0, 0, 0);
            acc1 = __builtin_amdgcn_mfma_i32_32x32x32_i8(a, b1, acc1, 0, 0, 0);
        }
    }

    int col0 = tn * 64 + lrow;
    int col1 = col0 + 32;
    float bi0 = bf1[col0], m0 = mf1[col0];
    float sc0 = gf1[col0] / sqrtf(vf1[col0] + 1e-5f), bb0 = bef1[col0];
    float bi1 = bf1[col1], m1 = mf1[col1];
    float sc1 = gf1[col1] / sqrtf(vf1[col1] + 1e-5f), bb1 = bef1[col1];
#pragma unroll
    for (int r = 0; r < 16; r++) {
        int row = tm * 128 + wid * 32 + (r & 3) + 8 * (r >> 2) + 4 * kh;
        float bn0 = ((float)acc0[r] + bi0 - m0) * sc0 + bb0;
        float bn1 = ((float)acc1[r] + bi1 - m1) * sc1 + bb1;
        act3[(size_t)row * 1024 + col0] = (signed char)fsign(bn0);
        act3[(size_t)row * 1024 + col1] = (signed char)fsign(bn1);
    }
}

// K4: fc2 (1024->10) + bias + BN + log_softmax. One wave per image.
__global__ void k4_fc2(const signed char* __restrict__ act3, const signed char* __restrict__ swf2,
                       const float* __restrict__ bf2, const float* __restrict__ gf2,
                       const float* __restrict__ bef2, const float* __restrict__ mf2,
                       const float* __restrict__ vf2, float* __restrict__ out) {
    int wid = (blockIdx.x * 256 + threadIdx.x) >> 6;
    int lane = threadIdx.x & 63;
    if (wid >= BATCH) return;
    const int* hd = (const int*)act3 + (size_t)wid * 256;
    const int* wd = (const int*)swf2;
    int acc[10];
#pragma unroll
    for (int o = 0; o < 10; o++) acc[o] = 0;
#pragma unroll
    for (int i = 0; i < 4; i++) {
        int k4 = i * 64 + lane;
        int hv = hd[k4];
#pragma unroll
        for (int o = 0; o < 10; o++)
            acc[o] = sdot4(hv, wd[o * 256 + k4], acc[o]);
    }
#pragma unroll
    for (int o = 0; o < 10; o++)
#pragma unroll
        for (int s = 32; s > 0; s >>= 1) acc[o] += __shfl_xor(acc[o], s);
    if (lane == 0) {
        float logit[10];
        float mx = -1e30f;
#pragma unroll
        for (int o = 0; o < 10; o++) {
            float z = (float)acc[o] + bf2[o];
            float bn = (z - mf2[o]) * (gf2[o] / sqrtf(vf2[o] + 1e-5f)) + bef2[o];
            logit[o] = bn;
            mx = fmaxf(mx, bn);
        }
        float s = 0.f;
#pragma unroll
        for (int o = 0; o < 10; o++) s += expf(logit[o] - mx);
        float lse = mx + logf(s);
#pragma unroll
        for (int o = 0; o < 10; o++) out[(size_t)wid * 10 + o] = logit[o] - lse;
    }
}

extern "C" void kernel_launch(void* const* d_in, const int* in_sizes, int n_in,
                              void* d_out, int out_size, void* d_ws, size_t ws_size,
                              hipStream_t stream) {
    const float* x   = (const float*)d_in[0];
    const float* w1  = (const float*)d_in[1];
    const float* b1  = (const float*)d_in[2];
    const float* g1  = (const float*)d_in[3];
    const float* be1 = (const float*)d_in[4];
    const float* m1  = (const float*)d_in[5];
    const float* v1  = (const float*)d_in[6];
    const float* w2  = (const float*)d_in[7];
    const float* b2  = (const float*)d_in[8];
    const float* g2  = (const float*)d_in[9];
    const float* be2 = (const float*)d_in[10];
    const float* m2  = (const float*)d_in[11];
    const float* v2  = (const float*)d_in[12];
    const float* wf1 = (const float*)d_in[13];
    const float* bf1 = (const float*)d_in[14];
    const float* gf1 = (const float*)d_in[15];
    const float* bef1= (const float*)d_in[16];
    const float* mf1 = (const float*)d_in[17];
    const float* vf1 = (const float*)d_in[18];
    const float* wf2 = (const float*)d_in[19];
    const float* bf2 = (const float*)d_in[20];
    const float* gf2 = (const float*)d_in[21];
    const float* bef2= (const float*)d_in[22];
    const float* mf2 = (const float*)d_in[23];
    const float* vf2 = (const float*)d_in[24];
    float* out = (float*)d_out;

    // ws layout (all int8 unless noted)
    char* ws = (char*)d_ws;
    signed char* act1 = (signed char*)ws;                  // 2048*169*32   = 11,075,584
    signed char* act2 = act1 + 11075584;                   // 2048*2304     =  4,718,592
    signed char* act3 = act2 + 4718592;                    // 2048*1024     =  2,097,152
    signed char* w2p  = act3 + 2097152;                    // 64*25*32      =     51,200
    signed char* wf1s = w2p + 51200;                       // 1024*2304     =  2,359,296
    signed char* wf2p = wf1s + 2359296;                    // 10*1024       =     10,240
    float* k1c = (float*)(wf2p + 10240);                   // 32*16 floats  =      2,048 B

    // fused prep: 2,359,296 + 51,200 + 10,240 + 416 = 2,421,152 elems
    prep_all<<<9458, 256, 0, stream>>>(w1, b1, g1, be1, m1, v1, w2, wf1, wf2,
                                       w2p, wf1s, wf2p, k1c);

    k1_conv1<<<2048, 256, 0, stream>>>(x, k1c, act1);

    k2_mfma<<<1024, 576, 0, stream>>>(act1, w2p, b2, g2, be2, m2, v2, act2);

    k3_mfma<<<256, 256, 0, stream>>>(act2, wf1s, bf1, gf1, bef1, mf1, vf1, act3);

    k4_fc2<<<512, 256, 0, stream>>>(act3, wf2p, bf2, gf2, bef2, mf2, vf2, out);
}